// Round 2
// baseline (16860.059 us; speedup 1.0000x reference)
//
#include <hip/hip_runtime.h>
#include <hip/hip_bf16.h>

typedef __hip_bfloat16 bf16;

#define TPB 256
#define CHUNK 32
#define COB 32

// ---- typed load/store helpers (compute in fp32) ---------------------------
__device__ inline float ldf(const float* p, size_t i) { return p[i]; }
__device__ inline float ldf(const bf16* p, size_t i)  { return __bfloat162float(p[i]); }
__device__ inline void  stf(float* p, size_t i, float v) { p[i] = v; }
__device__ inline void  stf(bf16* p, size_t i, float v)  { p[i] = __float2bfloat16(v); }

// ---------------------------------------------------------------------------
// Fused conv(KxK, pad K/2) + optional instance-norm + leaky-relu.
// grid = (N images, Cout/COB); block = 256 threads (one per spatial pos).
// MODE 0: norm+act, write out
// MODE 1: norm+act, out += (read-modify-write)
// MODE 2: conv1b routing: co<128 raw->out_s, 128..255 norm+act->out, >=256 raw->out_o
// GATHER: input = concat(obj_maps[s_idx], pred broadcast, obj_maps[o_idx])
// ---------------------------------------------------------------------------
template<int K, int MODE, bool GATHER, typename TIN, typename TOUT>
__global__ __launch_bounds__(TPB, 2) void conv_kernel(
    const TIN* __restrict__ in,
    const float* __restrict__ obj_maps,
    const float* __restrict__ pred_vecs,
    const int*  __restrict__ edges,
    const float* __restrict__ wf,    // (Cout, Cin, K, K) fp32
    const float* __restrict__ bfp,   // (Cout) fp32
    TOUT* __restrict__ out,
    bf16* __restrict__ out_s,
    bf16* __restrict__ out_o,
    int Cin, int Cout)
{
    const int n   = blockIdx.x;
    const int co0 = blockIdx.y * COB;
    const int tid = threadIdx.x;
    const int y = tid >> 4, x = tid & 15;

    __shared__ float tile[CHUNK * 324];           // 32 ch x 18x18 zero-padded
    __shared__ float red_s[COB * 4], red_s2[COB * 4];

    float acc[COB];
#pragma unroll
    for (int j = 0; j < COB; ++j) acc[j] = bfp[co0 + j];

    int s_idx = 0, o_idx = 0;
    if (GATHER) { s_idx = edges[2 * n]; o_idx = edges[2 * n + 1]; }

    const int nchunk = Cin / CHUNK;
    const int P = K / 2;

#pragma unroll 1
    for (int ch = 0; ch < nchunk; ++ch) {
        const int cc0 = ch * CHUNK;
        __syncthreads();   // protect previous tile consumers
#pragma unroll 1
        for (int idx = tid; idx < CHUNK * 324; idx += TPB) {
            int c   = idx / 324;
            int rem = idx - c * 324;
            int yy  = rem / 18;
            int xx  = rem - yy * 18;
            float v = 0.f;
            if (yy >= 1 && yy < 17 && xx >= 1 && xx < 17) {
                int pix = (yy - 1) * 16 + (xx - 1);
                int gc  = cc0 + c;
                if (GATHER) {
                    if (gc < 64)
                        v = obj_maps[(size_t)s_idx * 16384 + gc * 256 + pix];
                    else if (gc < 128)
                        v = pred_vecs[n * 64 + (gc - 64)];
                    else
                        v = obj_maps[(size_t)o_idx * 16384 + (gc - 128) * 256 + pix];
                } else {
                    v = ldf(in, (size_t)n * Cin * 256 + (size_t)gc * 256 + pix);
                }
            }
            tile[idx] = v;
        }
        __syncthreads();

#pragma unroll 1
        for (int ci = 0; ci < CHUNK; ++ci) {
            float iv[K * K];
#pragma unroll
            for (int dy = 0; dy < K; ++dy)
#pragma unroll
                for (int dx = 0; dx < K; ++dx)
                    iv[dy * K + dx] = tile[ci * 324 + (y + 1 + dy - P) * 18 + (x + 1 + dx - P)];
#pragma unroll
            for (int j = 0; j < COB; ++j) {
                const float* wp = wf + ((size_t)(co0 + j) * Cin + (cc0 + ci)) * (K * K);
#pragma unroll
                for (int k = 0; k < K * K; ++k) acc[j] += iv[k] * wp[k];
            }
        }
    }

    // ---------------- epilogue: instance norm + leaky relu ----------------
    const bool do_norm = (MODE == 2) ? (co0 >= 128 && co0 < 256) : true;
    if (do_norm) {
        const int lane = tid & 63, wave = tid >> 6;
#pragma unroll
        for (int j = 0; j < COB; ++j) {
            float s = acc[j], s2 = acc[j] * acc[j];
#pragma unroll
            for (int off = 32; off > 0; off >>= 1) {
                s  += __shfl_down(s, off, 64);
                s2 += __shfl_down(s2, off, 64);
            }
            if (lane == 0) { red_s[j * 4 + wave] = s; red_s2[j * 4 + wave] = s2; }
        }
        __syncthreads();
#pragma unroll
        for (int j = 0; j < COB; ++j) {
            float s  = red_s[j * 4] + red_s[j * 4 + 1] + red_s[j * 4 + 2] + red_s[j * 4 + 3];
            float s2 = red_s2[j * 4] + red_s2[j * 4 + 1] + red_s2[j * 4 + 2] + red_s2[j * 4 + 3];
            float m   = s * (1.f / 256.f);
            float var = s2 * (1.f / 256.f) - m * m;
            float r   = rsqrtf(var + 1e-5f);
            float v   = (acc[j] - m) * r;
            acc[j] = (v >= 0.f) ? v : 0.1f * v;
        }
    }

    if (MODE == 2) {
        if (co0 < 128) {
#pragma unroll
            for (int j = 0; j < COB; ++j)
                stf(out_s, (size_t)n * 32768 + (size_t)(co0 + j) * 256 + tid, acc[j]);
        } else if (co0 < 256) {
#pragma unroll
            for (int j = 0; j < COB; ++j)
                stf(out, (size_t)n * 32768 + (size_t)(co0 - 128 + j) * 256 + tid, acc[j]);
        } else {
#pragma unroll
            for (int j = 0; j < COB; ++j)
                stf(out_o, (size_t)n * 32768 + (size_t)(co0 - 256 + j) * 256 + tid, acc[j]);
        }
    } else if (MODE == 1) {
#pragma unroll
        for (int j = 0; j < COB; ++j) {
            size_t o = (size_t)n * Cout * 256 + (size_t)(co0 + j) * 256 + tid;
            stf(out, o, ldf((const TOUT*)out, o) + acc[j]);
        }
    } else {
#pragma unroll
        for (int j = 0; j < COB; ++j)
            stf(out, (size_t)n * Cout * 256 + (size_t)(co0 + j) * 256 + tid, acc[j]);
    }
}

// ---------------------------------------------------------------------------
// Deterministic segment-mean pooling: one block per object, scan edges into an
// LDS match list, then average new_s / new_o contributions.
// ---------------------------------------------------------------------------
__global__ __launch_bounds__(TPB) void pool_kernel(
    const int* __restrict__ edges,
    const bf16* __restrict__ new_s,
    const bf16* __restrict__ new_o,
    bf16* __restrict__ pooled)
{
    const int o = blockIdx.x;
    const int tid = threadIdx.x;
    __shared__ int list[2048];
    __shared__ int cnt;
    if (tid == 0) cnt = 0;
    __syncthreads();
    for (int t = tid; t < 1024; t += TPB) {
        int si = edges[2 * t], oi = edges[2 * t + 1];
        if (si == o) { int p = atomicAdd(&cnt, 1); list[p] = t * 2; }
        if (oi == o) { int p = atomicAdd(&cnt, 1); list[p] = t * 2 + 1; }
    }
    __syncthreads();
    const int c = cnt;
    const float inv = 1.f / fmaxf((float)c, 1.f);
    for (int e = tid; e < 128 * 256; e += TPB) {
        float s = 0.f;
        for (int m = 0; m < c; ++m) {
            int ent = list[m];
            int nn  = ent >> 1;
            const bf16* src = (ent & 1) ? new_o : new_s;
            s += __bfloat162float(src[(size_t)nn * 32768 + e]);
        }
        pooled[(size_t)o * 32768 + e] = __float2bfloat16(s * inv);
    }
}

// ---------------------------------------------------------------------------
extern "C" void kernel_launch(void* const* d_in, const int* in_sizes, int n_in,
                              void* d_out, int out_size, void* d_ws, size_t ws_size,
                              hipStream_t stream) {
    const float* obj_maps  = (const float*)d_in[0];   // (512,64,16,16) f32
    const float* pred_vecs = (const float*)d_in[1];   // (1024,64) f32
    const int*   edges     = (const int*)d_in[2];     // (1024,2) i32
    // d_in[3] obj_to_img: unused by reference
    const float* w1a = (const float*)d_in[4];  const float* b1a = (const float*)d_in[5];
    const float* w1b = (const float*)d_in[6];  const float* b1b = (const float*)d_in[7];
    const float* w2a = (const float*)d_in[8];  const float* b2a = (const float*)d_in[9];
    const float* w2b = (const float*)d_in[10]; const float* b2b = (const float*)d_in[11];
    const float* woa = (const float*)d_in[12]; const float* boa = (const float*)d_in[13];
    const float* wob = (const float*)d_in[14]; const float* bob = (const float*)d_in[15];

    float* out = (float*)d_out;                       // [new_obj | new_p] f32
    const size_t NP_OFF = (size_t)512 * 128 * 256;    // new_obj elements

    // ---- workspace arena (bf16 intermediates) ----
    char* ws = (char*)d_ws;
    size_t off = 0;
    auto alloc = [&](size_t bytes) -> char* {
        char* p = ws + off;
        off += (bytes + 255) & ~(size_t)255;
        return p;
    };
    const size_t SZ_T  = (size_t)1024 * 128 * 256 * 2;  // 67 MB
    char* Bt1   = alloc(SZ_T);       // t1; later: pooled (+0) and u1 (+33.5MB)
    char* Bnews = alloc(SZ_T);       // new_s; later: v1
    char* Bnewo = alloc(SZ_T);       // new_o

    bf16* t1     = (bf16*)Bt1;
    bf16* new_s  = (bf16*)Bnews;
    bf16* new_o  = (bf16*)Bnewo;
    bf16* pooled = (bf16*)Bt1;                                    // t1 dead after conv1b
    bf16* u1     = (bf16*)(Bt1 + (size_t)512 * 128 * 256 * 2);
    bf16* v1     = (bf16*)Bnews;                                  // new_s dead after pool

    // conv1a: gather(192) -> 128, 3x3, norm+act -> t1 (bf16)
    conv_kernel<3, 0, true, float, bf16><<<dim3(1024, 128 / COB), dim3(TPB), 0, stream>>>(
        (const float*)nullptr, obj_maps, pred_vecs, edges, w1a, b1a, t1, nullptr, nullptr, 192, 128);

    // conv1b: t1 128 -> 384, 3x3; split new_s(bf16) / new_p(norm+act -> d_out f32) / new_o(bf16)
    conv_kernel<3, 2, false, bf16, float><<<dim3(1024, 384 / COB), dim3(TPB), 0, stream>>>(
        t1, nullptr, nullptr, nullptr, w1b, b1b, out + NP_OFF, new_s, new_o, 128, 384);

    // segment-mean pooling -> pooled (512,128,16,16) bf16
    pool_kernel<<<dim3(512), dim3(TPB), 0, stream>>>(edges, new_s, new_o, pooled);

    // conv2a: pooled 128 -> 128, 3x3, norm+act -> u1 (bf16)
    conv_kernel<3, 0, false, bf16, bf16><<<dim3(512, 128 / COB), dim3(TPB), 0, stream>>>(
        pooled, nullptr, nullptr, nullptr, w2a, b2a, u1, nullptr, nullptr, 128, 128);

    // conv2b: u1 128 -> 128, 1x1, norm+act -> d_out[new_obj] f32 (overwrite)
    conv_kernel<1, 0, false, bf16, float><<<dim3(512, 128 / COB), dim3(TPB), 0, stream>>>(
        u1, nullptr, nullptr, nullptr, w2b, b2b, out, nullptr, nullptr, 128, 128);

    // convoa: obj_maps(f32) 64 -> 128, 3x3, norm+act -> v1 (bf16)
    conv_kernel<3, 0, false, float, bf16><<<dim3(512, 128 / COB), dim3(TPB), 0, stream>>>(
        obj_maps, nullptr, nullptr, nullptr, woa, boa, v1, nullptr, nullptr, 64, 128);

    // convob: v1 128 -> 128, 1x1, norm+act, d_out[new_obj] += (f32)
    conv_kernel<1, 1, false, bf16, float><<<dim3(512, 128 / COB), dim3(TPB), 0, stream>>>(
        v1, nullptr, nullptr, nullptr, wob, bob, out, nullptr, nullptr, 128, 128);
}

// Round 3
// 3032.031 us; speedup vs baseline: 5.5606x; 5.5606x over previous
//
#include <hip/hip_runtime.h>
#include <hip/hip_bf16.h>

typedef __hip_bfloat16 bf16;
typedef __attribute__((ext_vector_type(8))) short short8;
typedef __attribute__((ext_vector_type(4))) float float4v;

#define TPB 256

__device__ inline float ldf(const float* p, size_t i) { return p[i]; }
__device__ inline float ldf(const bf16* p, size_t i)  { return __bfloat162float(p[i]); }
__device__ inline void  stf(float* p, size_t i, float v) { p[i] = v; }
__device__ inline void  stf(bf16* p, size_t i, float v)  { p[i] = __float2bfloat16(v); }
__device__ inline short f2bs(float v) {
    __hip_bfloat16 h = __float2bfloat16(v);
    return *reinterpret_cast<short*>(&h);
}

// ---------------------------------------------------------------------------
// MFMA implicit-GEMM conv (KxK, pad K/2) + fused instance-norm + leaky-relu.
// grid = (N images, Cout/64). block = 256 thr = 4 waves.
// Per block: M=256 spatial x N=64 outch. Wave w: rows [w*64,w*64+64), all 64 n.
// K-loop: Cin chunks of 32 x taps; A,B staged in LDS bf16, ds_read_b128 frags.
// MODE 0: norm+act -> out.  MODE 1: norm+act, out += (f32 rmw).
// MODE 2 (conv1b): n0<128 raw->out_s(bf16); 128..255 norm+act->out(f32); else raw->out_o.
// GATHER: input = concat(obj_maps[s], pred bcast, obj_maps[o]) per edge.
// ---------------------------------------------------------------------------
template<int K, int MODE, bool GATHER, typename TIN, typename TOUT>
__global__ __launch_bounds__(TPB, 2) void mconv_kernel(
    const TIN* __restrict__ in,
    const float* __restrict__ obj_maps,
    const float* __restrict__ pred_vecs,
    const int*  __restrict__ edges,
    const float* __restrict__ wf,    // (Cout, Cin, K, K) f32
    const float* __restrict__ bfp,   // (Cout) f32
    TOUT* __restrict__ out,
    bf16* __restrict__ out_s,
    bf16* __restrict__ out_o,
    int Cin, int Cout)
{
    constexpr int P    = K / 2;
    constexpr int W    = 16 + 2 * P;       // padded tile width
    constexpr int TAPS = K * K;
    constexpr int CS   = 40;               // channel stride (pad 32->40, 80B, 16B aligned)

    __shared__ __align__(16) short Ash[W * W * CS];      // input chunk, pixel-major
    __shared__ __align__(16) short Bsh[TAPS * 64 * CS];  // weights [tap][n][ci]
    __shared__ float redS[256], redS2[256];

    const int n    = blockIdx.x;
    const int n0   = blockIdx.y * 64;
    const int tid  = threadIdx.x;
    const int lane = tid & 63;
    const int wv   = tid >> 6;
    const int quad = lane >> 4;
    const int l16  = lane & 15;

    // zero A buffer once (border + pad columns stay 0 forever)
    for (int i = tid; i < W * W * CS / 2; i += TPB) ((int*)Ash)[i] = 0;

    // acc init with bias (C-layout: col=n depends only on l16)
    float4v acc[4][4];
#pragma unroll
    for (int nt = 0; nt < 4; ++nt) {
        float b = bfp[n0 + nt * 16 + l16];
#pragma unroll
        for (int mt = 0; mt < 4; ++mt) acc[mt][nt] = float4v{b, b, b, b};
    }

    int s_idx = 0, o_idx = 0;
    if (GATHER) { s_idx = edges[2 * n]; o_idx = edges[2 * n + 1]; }

    const int y0 = tid >> 4, x0 = tid & 15;                 // staging pixel = tid
    const int abase = ((y0 + P) * W + (x0 + P)) * CS;

    for (int cc0 = 0; cc0 < Cin; cc0 += 32) {
        __syncthreads();
        // ---- stage A: 32 ch x 256 pix, convert to bf16, pixel-major ----
#pragma unroll 4
        for (int ch = 0; ch < 32; ++ch) {
            float v;
            if (GATHER) {
                int gc = cc0 + ch;
                if (gc < 64)
                    v = obj_maps[(size_t)s_idx * 16384 + gc * 256 + tid];
                else if (gc < 128)
                    v = pred_vecs[n * 64 + (gc - 64)];
                else
                    v = obj_maps[(size_t)o_idx * 16384 + (gc - 128) * 256 + tid];
            } else {
                v = ldf(in, ((size_t)n * Cin + cc0 + ch) * 256 + tid);
            }
            Ash[abase + ch] = f2bs(v);
        }
        // ---- stage B: 64 n x 32 ci x TAPS ----
        const size_t wrow = (size_t)Cin * TAPS;
#pragma unroll 1
        for (int idx = tid; idx < 64 * 32 * TAPS; idx += TPB) {
            int nn  = idx / (32 * TAPS);
            int rem = idx - nn * (32 * TAPS);
            int ci  = rem / TAPS;
            int tap = rem - ci * TAPS;
            float v = wf[(size_t)(n0 + nn) * wrow + (size_t)cc0 * TAPS + rem];
            Bsh[(tap * 64 + nn) * CS + ci] = f2bs(v);
        }
        __syncthreads();

        // ---- compute: taps x (4 B-frags, 4x4 MFMA) ----
#pragma unroll 1
        for (int tap = 0; tap < TAPS; ++tap) {
            const int dy = (K == 3) ? tap / 3 : 0;
            const int dx = (K == 3) ? tap - dy * 3 : 0;
            short8 bfr[4];
#pragma unroll
            for (int nt = 0; nt < 4; ++nt)
                bfr[nt] = *(const short8*)&Bsh[(tap * 64 + nt * 16 + l16) * CS + quad * 8];
#pragma unroll
            for (int mt = 0; mt < 4; ++mt) {
                int m = wv * 64 + mt * 16 + l16;
                int pix = ((m >> 4) + dy) * W + ((m & 15) + dx);
                short8 afr = *(const short8*)&Ash[pix * CS + quad * 8];
#pragma unroll
                for (int nt = 0; nt < 4; ++nt)
                    acc[mt][nt] = __builtin_amdgcn_mfma_f32_16x16x32_bf16(
                        afr, bfr[nt], acc[mt][nt], 0, 0, 0);
            }
        }
    }

    // ---------------- epilogue ----------------
    const bool do_norm = (MODE == 2) ? (n0 >= 128 && n0 < 256) : true;
    float mean[4], rstd[4];
    if (do_norm) {
#pragma unroll
        for (int nt = 0; nt < 4; ++nt) {
            float s = 0.f, s2 = 0.f;
#pragma unroll
            for (int mt = 0; mt < 4; ++mt)
#pragma unroll
                for (int r = 0; r < 4; ++r) {
                    float v = acc[mt][nt][r];
                    s += v; s2 += v * v;
                }
            s  += __shfl_xor(s, 16, 64);  s  += __shfl_xor(s, 32, 64);
            s2 += __shfl_xor(s2, 16, 64); s2 += __shfl_xor(s2, 32, 64);
            if (quad == 0) {
                redS [wv * 64 + nt * 16 + l16] = s;
                redS2[wv * 64 + nt * 16 + l16] = s2;
            }
        }
        __syncthreads();
#pragma unroll
        for (int nt = 0; nt < 4; ++nt) {
            int c = nt * 16 + l16;
            float s  = redS [c] + redS [64 + c] + redS [128 + c] + redS [192 + c];
            float s2 = redS2[c] + redS2[64 + c] + redS2[128 + c] + redS2[192 + c];
            float m  = s * (1.f / 256.f);
            float var = s2 * (1.f / 256.f) - m * m;
            mean[nt] = m;
            rstd[nt] = rsqrtf(var + 1e-5f);
        }
    }

    // LDS-transpose store, 16 channels at a time (reuse Ash as f32 [16][260])
    float* T = (float*)Ash;
    const int ch16 = tid >> 4;
    const int px0  = (tid & 15) * 16;
#pragma unroll 1
    for (int nt = 0; nt < 4; ++nt) {
        __syncthreads();
#pragma unroll
        for (int mt = 0; mt < 4; ++mt)
#pragma unroll
            for (int r = 0; r < 4; ++r) {
                float v = acc[mt][nt][r];
                if (do_norm) {
                    v = (v - mean[nt]) * rstd[nt];
                    v = (v >= 0.f) ? v : 0.1f * v;
                }
                T[l16 * 260 + wv * 64 + mt * 16 + quad * 4 + r] = v;
            }
        __syncthreads();
        const float* Tp = &T[ch16 * 260 + px0];
        const int gch = n0 + nt * 16 + ch16;
        if (MODE == 2) {
            if (n0 < 128) {
                bf16* dst = out_s + ((size_t)n * 128 + gch) * 256 + px0;
#pragma unroll
                for (int i = 0; i < 16; ++i) dst[i] = __float2bfloat16(Tp[i]);
            } else if (n0 < 256) {
                float* dst = (float*)out + ((size_t)n * 128 + (gch - 128)) * 256 + px0;
#pragma unroll
                for (int i = 0; i < 16; ++i) dst[i] = Tp[i];
            } else {
                bf16* dst = out_o + ((size_t)n * 128 + (gch - 256)) * 256 + px0;
#pragma unroll
                for (int i = 0; i < 16; ++i) dst[i] = __float2bfloat16(Tp[i]);
            }
        } else if (MODE == 1) {
            float* dst = (float*)out + ((size_t)n * Cout + gch) * 256 + px0;
#pragma unroll
            for (int i = 0; i < 16; ++i) dst[i] = dst[i] + Tp[i];
        } else {
            TOUT* dst = out + ((size_t)n * Cout + gch) * 256 + px0;
#pragma unroll
            for (int i = 0; i < 16; ++i) stf(dst, i, Tp[i]);
        }
    }
}

// ---------------------------------------------------------------------------
// Deterministic segment-mean pooling (unchanged from round 2).
// ---------------------------------------------------------------------------
__global__ __launch_bounds__(TPB) void pool_kernel(
    const int* __restrict__ edges,
    const bf16* __restrict__ new_s,
    const bf16* __restrict__ new_o,
    bf16* __restrict__ pooled)
{
    const int o = blockIdx.x;
    const int tid = threadIdx.x;
    __shared__ int list[2048];
    __shared__ int cnt;
    if (tid == 0) cnt = 0;
    __syncthreads();
    for (int t = tid; t < 1024; t += TPB) {
        int si = edges[2 * t], oi = edges[2 * t + 1];
        if (si == o) { int p = atomicAdd(&cnt, 1); list[p] = t * 2; }
        if (oi == o) { int p = atomicAdd(&cnt, 1); list[p] = t * 2 + 1; }
    }
    __syncthreads();
    const int c = cnt;
    const float inv = 1.f / fmaxf((float)c, 1.f);
    for (int e = tid; e < 128 * 256; e += TPB) {
        float s = 0.f;
        for (int m = 0; m < c; ++m) {
            int ent = list[m];
            int nn  = ent >> 1;
            const bf16* src = (ent & 1) ? new_o : new_s;
            s += __bfloat162float(src[(size_t)nn * 32768 + e]);
        }
        pooled[(size_t)o * 32768 + e] = __float2bfloat16(s * inv);
    }
}

// ---------------------------------------------------------------------------
extern "C" void kernel_launch(void* const* d_in, const int* in_sizes, int n_in,
                              void* d_out, int out_size, void* d_ws, size_t ws_size,
                              hipStream_t stream) {
    const float* obj_maps  = (const float*)d_in[0];   // (512,64,16,16) f32
    const float* pred_vecs = (const float*)d_in[1];   // (1024,64) f32
    const int*   edges     = (const int*)d_in[2];     // (1024,2) i32
    const float* w1a = (const float*)d_in[4];  const float* b1a = (const float*)d_in[5];
    const float* w1b = (const float*)d_in[6];  const float* b1b = (const float*)d_in[7];
    const float* w2a = (const float*)d_in[8];  const float* b2a = (const float*)d_in[9];
    const float* w2b = (const float*)d_in[10]; const float* b2b = (const float*)d_in[11];
    const float* woa = (const float*)d_in[12]; const float* boa = (const float*)d_in[13];
    const float* wob = (const float*)d_in[14]; const float* bob = (const float*)d_in[15];

    float* out = (float*)d_out;                       // [new_obj | new_p] f32
    const size_t NP_OFF = (size_t)512 * 128 * 256;

    char* ws = (char*)d_ws;
    size_t off = 0;
    auto alloc = [&](size_t bytes) -> char* {
        char* p = ws + off;
        off += (bytes + 255) & ~(size_t)255;
        return p;
    };
    const size_t SZ_T = (size_t)1024 * 128 * 256 * 2;   // 67 MB
    char* Bt1   = alloc(SZ_T);
    char* Bnews = alloc(SZ_T);
    char* Bnewo = alloc(SZ_T);

    bf16* t1     = (bf16*)Bt1;
    bf16* new_s  = (bf16*)Bnews;
    bf16* new_o  = (bf16*)Bnewo;
    bf16* pooled = (bf16*)Bt1;                                   // t1 dead after conv1b
    bf16* u1     = (bf16*)(Bt1 + (size_t)512 * 128 * 256 * 2);
    bf16* v1     = (bf16*)Bnews;                                 // new_s dead after pool

    // conv1a: gather(192) -> 128, 3x3, norm+act -> t1 (bf16)
    mconv_kernel<3, 0, true, float, bf16><<<dim3(1024, 2), dim3(TPB), 0, stream>>>(
        (const float*)nullptr, obj_maps, pred_vecs, edges, w1a, b1a, t1, nullptr, nullptr, 192, 128);

    // conv1b: t1 128 -> 384, 3x3; split new_s / new_p(norm+act, f32 d_out) / new_o
    mconv_kernel<3, 2, false, bf16, float><<<dim3(1024, 6), dim3(TPB), 0, stream>>>(
        t1, nullptr, nullptr, nullptr, w1b, b1b, out + NP_OFF, new_s, new_o, 128, 384);

    // segment-mean pooling -> pooled (512,128,16,16) bf16
    pool_kernel<<<dim3(512), dim3(TPB), 0, stream>>>(edges, new_s, new_o, pooled);

    // conv2a: pooled 128 -> 128, 3x3, norm+act -> u1 (bf16)
    mconv_kernel<3, 0, false, bf16, bf16><<<dim3(512, 2), dim3(TPB), 0, stream>>>(
        pooled, nullptr, nullptr, nullptr, w2a, b2a, u1, nullptr, nullptr, 128, 128);

    // conv2b: u1 128 -> 128, 1x1, norm+act -> d_out[new_obj] (overwrite)
    mconv_kernel<1, 0, false, bf16, float><<<dim3(512, 2), dim3(TPB), 0, stream>>>(
        u1, nullptr, nullptr, nullptr, w2b, b2b, out, nullptr, nullptr, 128, 128);

    // convoa: obj_maps(f32) 64 -> 128, 3x3, norm+act -> v1 (bf16)
    mconv_kernel<3, 0, false, float, bf16><<<dim3(512, 2), dim3(TPB), 0, stream>>>(
        obj_maps, nullptr, nullptr, nullptr, woa, boa, v1, nullptr, nullptr, 64, 128);

    // convob: v1 128 -> 128, 1x1, norm+act, d_out[new_obj] += (f32)
    mconv_kernel<1, 1, false, bf16, float><<<dim3(512, 2), dim3(TPB), 0, stream>>>(
        v1, nullptr, nullptr, nullptr, wob, bob, out, nullptr, nullptr, 128, 128);
}